// Round 7
// baseline (95.435 us; speedup 1.0000x reference)
//
#include <hip/hip_runtime.h>

#define NN 512
#define TT 8
#define DD 64

typedef float v2f __attribute__((ext_vector_type(2)));

// ---------------------------------------------------------------------------
// Kernel 1: projection.  (unchanged, est. 1-3 us)
//   L[t][n][h] = sum_d x[n][t][d] * W1[d][h]
//   R[t][n][h] = sum_d x[n][t][d] * W1[64+d][h] + b1[h]
// ---------------------------------------------------------------------------
__global__ __launch_bounds__(256) void k1_proj(const float* __restrict__ x,
                                               const float* __restrict__ W1,
                                               const float* __restrict__ b1,
                                               float* __restrict__ L,
                                               float* __restrict__ R)
{
    int g    = blockIdx.x * 256 + threadIdx.x;   // 0..131071
    int c    = g & 127;
    int h    = c & 63;
    int half = c >> 6;            // 0 -> L, 1 -> R
    int pair = g >> 7;            // 0..1023
    int n    = pair >> 1;         // 0..511
    int t0   = (pair & 1) * 4;

    float wcol[DD];
    const float* wbase = W1 + (half << 6) * DD + h;
#pragma unroll
    for (int d = 0; d < DD; ++d) wcol[d] = wbase[d << 6];

    float bias = half ? b1[h] : 0.0f;
    float* outbase = half ? R : L;

#pragma unroll
    for (int tt = 0; tt < 4; ++tt) {
        int t = t0 + tt;
        const float4* xr = (const float4*)(x + n * (TT * DD) + t * DD);
        float acc = 0.0f;
#pragma unroll
        for (int d4 = 0; d4 < 16; ++d4) {
            float4 xv = xr[d4];
            acc = fmaf(xv.x, wcol[d4 * 4 + 0], acc);
            acc = fmaf(xv.y, wcol[d4 * 4 + 1], acc);
            acc = fmaf(xv.z, wcol[d4 * 4 + 2], acc);
            acc = fmaf(xv.w, wcol[d4 * 4 + 3], acc);
        }
        outbase[t * (NN * DD) + n * DD + h] = acc + bias;
    }
}

// ---------------------------------------------------------------------------
// Kernel 2 (v5): R5 structure (both panels in 128KB dynamic LDS, 8 waves,
// wave w owns t=w, 4x4 outputs/lane) + packed-f32 inner loop (v_pk_add_f32 /
// v_pk_fma_f32 via float2 ext-vectors; relu max stays scalar — no packed f32
// max on CDNA). LAUNCHED TWICE this round as a timing probe: k2 is
// idempotent, so dur_us - 84.0 ~= one k2 instance.
// ---------------------------------------------------------------------------
__global__ __launch_bounds__(512) void k2_main(const float* __restrict__ L,
                                               const float* __restrict__ R,
                                               const float* __restrict__ W2,
                                               const float* __restrict__ b2,
                                               const float* __restrict__ a,
                                               float* __restrict__ A)
{
    extern __shared__ float S[];
    // floats: L tile t at t*2048, R tile t at 16384 + t*2048, w2s at 32768.
    float* const w2s = S + 32768;

    const int tid = threadIdx.x;
    const int i0  = blockIdx.y << 5;
    const int j0  = blockIdx.x << 5;

    // ---- stage all 8 t-tiles of L(i-rows) and R(j-rows): 8192 float4
#pragma unroll
    for (int k = 0; k < 16; ++k) {
        int e    = tid + (k << 9);    // 0..8191
        int half = e >> 12;           // 0: L, 1: R
        int q    = e & 4095;
        int t    = q >> 9;
        int w    = q & 511;
        int row  = w >> 4;
        int c4   = w & 15;
        const float* src = half ? (R + t * (NN * DD) + (j0 + row) * DD)
                                : (L + t * (NN * DD) + (i0 + row) * DD);
        float4 v = ((const float4*)src)[c4];
        float* dst = S + (half ? 16384 : 0) + t * 2048 + (row << 6)
                       + ((c4 ^ ((row >> 1) & 7)) << 2);
        *(float4*)dst = v;
    }
    if (tid < 64) w2s[tid] = W2[tid];

    const int wv   = tid >> 6;        // wave id == t
    const int lane = tid & 63;
    const int tjx  = lane & 7;
    const int tiy  = lane >> 3;

    float wt;
    {
        float av[8];
#pragma unroll
        for (int t = 0; t < 8; ++t) av[t] = a[t];
        float m = av[0];
#pragma unroll
        for (int t = 1; t < 8; ++t) m = fmaxf(m, av[t]);
        float ssum = 0.0f;
#pragma unroll
        for (int t = 0; t < 8; ++t) ssum += expf(av[t] - m);
        wt = expf(av[wv] - m) / ssum
           * (1.0f + 0.5f * expf(-0.1f * (float)(7 - wv)));
    }
    const float b2v = b2[0];

    __syncthreads();

    const float* LB = S + wv * 2048;
    const float* RB = S + 16384 + wv * 2048;

    int lbase[4], rbase[4], lsw[4], rsw[4];
#pragma unroll
    for (int r = 0; r < 4; ++r) {
        int li = 4 * tiy + r;
        int rj = 4 * tjx + r;
        lbase[r] = li << 6;  lsw[r] = (li >> 1) & 7;
        rbase[r] = rj << 6;  rsw[r] = (rj >> 1) & 7;
    }

    v2f acc2[4][4];
#pragma unroll
    for (int p = 0; p < 4; ++p)
#pragma unroll
        for (int q = 0; q < 4; ++q) acc2[p][q] = (v2f){0.0f, 0.0f};

#pragma unroll 4
    for (int d4 = 0; d4 < 16; ++d4) {
        float4 lv[4], rv[4];
#pragma unroll
        for (int r = 0; r < 4; ++r)
            lv[r] = *(const float4*)(LB + lbase[r] + ((d4 ^ lsw[r]) << 2));
#pragma unroll
        for (int r = 0; r < 4; ++r)
            rv[r] = *(const float4*)(RB + rbase[r] + ((d4 ^ rsw[r]) << 2));
        float4 w4 = *(const float4*)(w2s + (d4 << 2));
        v2f w0 = (v2f){w4.x, w4.y};
        v2f w1 = (v2f){w4.z, w4.w};
        v2f lp0[4], lp1[4], rq0[4], rq1[4];
#pragma unroll
        for (int r = 0; r < 4; ++r) {
            lp0[r] = (v2f){lv[r].x, lv[r].y};
            lp1[r] = (v2f){lv[r].z, lv[r].w};
            rq0[r] = (v2f){rv[r].x, rv[r].y};
            rq1[r] = (v2f){rv[r].z, rv[r].w};
        }
#pragma unroll
        for (int p = 0; p < 4; ++p) {
#pragma unroll
            for (int q = 0; q < 4; ++q) {
                v2f m0 = lp0[p] + rq0[q];              // v_pk_add_f32
                m0[0] = fmaxf(m0[0], 0.0f);
                m0[1] = fmaxf(m0[1], 0.0f);
                v2f m1 = lp1[p] + rq1[q];
                m1[0] = fmaxf(m1[0], 0.0f);
                m1[1] = fmaxf(m1[1], 0.0f);
                acc2[p][q] = m0 * w0 + (m1 * w1 + acc2[p][q]);  // 2x v_pk_fma_f32
            }
        }
    }

    // ---- epilogue per wave: relu + weight, dump partial into LDS
    __syncthreads();
    float* const P = S;               // 8 x 1024 floats, aliases dead tiles
#pragma unroll
    for (int p = 0; p < 4; ++p) {
        float sc[4];
#pragma unroll
        for (int q = 0; q < 4; ++q)
            sc[q] = wt * fmaxf(acc2[p][q][0] + acc2[p][q][1] + b2v, 0.0f);
        *(float4*)(P + (wv << 10) + ((4 * tiy + p) << 5) + (tjx << 2)) =
            make_float4(sc[0], sc[1], sc[2], sc[3]);
    }
    __syncthreads();

    // ---- cross-t reduce + store
#pragma unroll
    for (int e = tid; e < 1024; e += 512) {
        float s = 0.0f;
#pragma unroll
        for (int t = 0; t < 8; ++t) s += P[(t << 10) + e];
        A[(i0 + (e >> 5)) * NN + j0 + (e & 31)] = s;
    }
}

extern "C" void kernel_launch(void* const* d_in, const int* in_sizes, int n_in,
                              void* d_out, int out_size, void* d_ws, size_t ws_size,
                              hipStream_t stream) {
    const float* x  = (const float*)d_in[0];
    const float* W1 = (const float*)d_in[1];
    const float* b1 = (const float*)d_in[2];
    const float* W2 = (const float*)d_in[3];
    const float* b2 = (const float*)d_in[4];
    const float* a  = (const float*)d_in[5];
    float* A = (float*)d_out;

    float* L = (float*)d_ws;                 // 1 MB
    float* R = L + NN * TT * DD;             // 1 MB

    k1_proj<<<512, 256, 0, stream>>>(x, W1, b1, L, R);

    size_t ldsBytes = (32768 + 64) * sizeof(float);   // ~128.3 KB
    // PROBE: k2 launched twice (idempotent). dur_us - 84.0 ~= one k2.
    k2_main<<<dim3(16, 16), 512, ldsBytes, stream>>>(L, R, W2, b2, a, A);
    k2_main<<<dim3(16, 16), 512, ldsBytes, stream>>>(L, R, W2, b2, a, A);
}

// Round 10
// 86.244 us; speedup vs baseline: 1.1066x; 1.1066x over previous
//
#include <hip/hip_runtime.h>

#define NN 512
#define TT 8
#define DD 64

typedef float v2f __attribute__((ext_vector_type(2)));

// ---------------------------------------------------------------------------
// Kernel 1: projection (~1.5 us measured-consistent).
//   L[t][n][h] = sum_d x[n][t][d] * W1[d][h]
//   R[t][n][h] = sum_d x[n][t][d] * W1[64+d][h] + b1[h]
// ---------------------------------------------------------------------------
__global__ __launch_bounds__(256) void k1_proj(const float* __restrict__ x,
                                               const float* __restrict__ W1,
                                               const float* __restrict__ b1,
                                               float* __restrict__ L,
                                               float* __restrict__ R)
{
    int g    = blockIdx.x * 256 + threadIdx.x;   // 0..131071
    int c    = g & 127;
    int h    = c & 63;
    int half = c >> 6;            // 0 -> L, 1 -> R
    int pair = g >> 7;            // 0..1023
    int n    = pair >> 1;         // 0..511
    int t0   = (pair & 1) * 4;

    float wcol[DD];
    const float* wbase = W1 + (half << 6) * DD + h;
#pragma unroll
    for (int d = 0; d < DD; ++d) wcol[d] = wbase[d << 6];

    float bias = half ? b1[h] : 0.0f;
    float* outbase = half ? R : L;

#pragma unroll
    for (int tt = 0; tt < 4; ++tt) {
        int t = t0 + tt;
        const float4* xr = (const float4*)(x + n * (TT * DD) + t * DD);
        float acc = 0.0f;
#pragma unroll
        for (int d4 = 0; d4 < 16; ++d4) {
            float4 xv = xr[d4];
            acc = fmaf(xv.x, wcol[d4 * 4 + 0], acc);
            acc = fmaf(xv.y, wcol[d4 * 4 + 1], acc);
            acc = fmaf(xv.z, wcol[d4 * 4 + 2], acc);
            acc = fmaf(xv.w, wcol[d4 * 4 + 3], acc);
        }
        outbase[t * (NN * DD) + n * DD + h] = acc + bias;
    }
}

// ---------------------------------------------------------------------------
// Kernel 2 (v6): measured ~11.4 us (R7 duplicate-launch probe). LDS-pipe
// bound: 8 waves x 144 ds_read_b128 x 12cyc ~= 5.8us floor; packed VALU 3.4us
// overlaps. Structure (32x32 tile, wave-per-t, 4x4/lane, 128KB LDS) is the
// read-per-acc optimum under the 160KB LDS cap and 256-block grid. This
// round: unroll 8 (ds_read ILP at 2 waves/SIMD) + float4 epilogue reduce.
// ---------------------------------------------------------------------------
__global__ __launch_bounds__(512) void k2_main(const float* __restrict__ L,
                                               const float* __restrict__ R,
                                               const float* __restrict__ W2,
                                               const float* __restrict__ b2,
                                               const float* __restrict__ a,
                                               float* __restrict__ A)
{
    extern __shared__ float S[];
    // floats: L tile t at t*2048, R tile t at 16384 + t*2048, w2s at 32768.
    float* const w2s = S + 32768;

    const int tid = threadIdx.x;
    const int i0  = blockIdx.y << 5;
    const int j0  = blockIdx.x << 5;

    // ---- stage all 8 t-tiles of L(i-rows) and R(j-rows): 8192 float4
#pragma unroll
    for (int k = 0; k < 16; ++k) {
        int e    = tid + (k << 9);    // 0..8191
        int half = e >> 12;           // 0: L, 1: R
        int q    = e & 4095;
        int t    = q >> 9;
        int w    = q & 511;
        int row  = w >> 4;
        int c4   = w & 15;
        const float* src = half ? (R + t * (NN * DD) + (j0 + row) * DD)
                                : (L + t * (NN * DD) + (i0 + row) * DD);
        float4 v = ((const float4*)src)[c4];
        float* dst = S + (half ? 16384 : 0) + t * 2048 + (row << 6)
                       + ((c4 ^ ((row >> 1) & 7)) << 2);
        *(float4*)dst = v;
    }
    if (tid < 64) w2s[tid] = W2[tid];

    const int wv   = tid >> 6;        // wave id == t
    const int lane = tid & 63;
    const int tjx  = lane & 7;
    const int tiy  = lane >> 3;

    float wt;
    {
        float av[8];
#pragma unroll
        for (int t = 0; t < 8; ++t) av[t] = a[t];
        float m = av[0];
#pragma unroll
        for (int t = 1; t < 8; ++t) m = fmaxf(m, av[t]);
        float ssum = 0.0f;
#pragma unroll
        for (int t = 0; t < 8; ++t) ssum += expf(av[t] - m);
        wt = expf(av[wv] - m) / ssum
           * (1.0f + 0.5f * expf(-0.1f * (float)(7 - wv)));
    }
    const float b2v = b2[0];

    __syncthreads();

    const float* LB = S + wv * 2048;
    const float* RB = S + 16384 + wv * 2048;

    int lbase[4], rbase[4], lsw[4], rsw[4];
#pragma unroll
    for (int r = 0; r < 4; ++r) {
        int li = 4 * tiy + r;
        int rj = 4 * tjx + r;
        lbase[r] = li << 6;  lsw[r] = (li >> 1) & 7;
        rbase[r] = rj << 6;  rsw[r] = (rj >> 1) & 7;
    }

    v2f acc2[4][4];
#pragma unroll
    for (int p = 0; p < 4; ++p)
#pragma unroll
        for (int q = 0; q < 4; ++q) acc2[p][q] = (v2f){0.0f, 0.0f};

#pragma unroll 8
    for (int d4 = 0; d4 < 16; ++d4) {
        float4 lv[4], rv[4];
#pragma unroll
        for (int r = 0; r < 4; ++r)
            lv[r] = *(const float4*)(LB + lbase[r] + ((d4 ^ lsw[r]) << 2));
#pragma unroll
        for (int r = 0; r < 4; ++r)
            rv[r] = *(const float4*)(RB + rbase[r] + ((d4 ^ rsw[r]) << 2));
        float4 w4 = *(const float4*)(w2s + (d4 << 2));
        v2f w0 = (v2f){w4.x, w4.y};
        v2f w1 = (v2f){w4.z, w4.w};
        v2f lp0[4], lp1[4], rq0[4], rq1[4];
#pragma unroll
        for (int r = 0; r < 4; ++r) {
            lp0[r] = (v2f){lv[r].x, lv[r].y};
            lp1[r] = (v2f){lv[r].z, lv[r].w};
            rq0[r] = (v2f){rv[r].x, rv[r].y};
            rq1[r] = (v2f){rv[r].z, rv[r].w};
        }
#pragma unroll
        for (int p = 0; p < 4; ++p) {
#pragma unroll
            for (int q = 0; q < 4; ++q) {
                v2f m0 = lp0[p] + rq0[q];              // v_pk_add_f32
                m0[0] = fmaxf(m0[0], 0.0f);
                m0[1] = fmaxf(m0[1], 0.0f);
                v2f m1 = lp1[p] + rq1[q];
                m1[0] = fmaxf(m1[0], 0.0f);
                m1[1] = fmaxf(m1[1], 0.0f);
                acc2[p][q] = m0 * w0 + (m1 * w1 + acc2[p][q]);  // 2x v_pk_fma_f32
            }
        }
    }

    // ---- epilogue per wave: relu + weight, dump partial into LDS
    __syncthreads();
    float* const P = S;               // 8 x 1024 floats, aliases dead tiles
#pragma unroll
    for (int p = 0; p < 4; ++p) {
        float sc[4];
#pragma unroll
        for (int q = 0; q < 4; ++q)
            sc[q] = wt * fmaxf(acc2[p][q][0] + acc2[p][q][1] + b2v, 0.0f);
        *(float4*)(P + (wv << 10) + ((4 * tiy + p) << 5) + (tjx << 2)) =
            make_float4(sc[0], sc[1], sc[2], sc[3]);
    }
    __syncthreads();

    // ---- cross-t reduce + store: 256 threads, one float4 each (b128 reads)
    if (tid < 256) {
        float4 s = make_float4(0.f, 0.f, 0.f, 0.f);
#pragma unroll
        for (int t = 0; t < 8; ++t) {
            float4 p = *(const float4*)(P + (t << 10) + (tid << 2));
            s.x += p.x; s.y += p.y; s.z += p.z; s.w += p.w;
        }
        *(float4*)(A + (i0 + (tid >> 3)) * NN + j0 + ((tid & 7) << 2)) = s;
    }
}

extern "C" void kernel_launch(void* const* d_in, const int* in_sizes, int n_in,
                              void* d_out, int out_size, void* d_ws, size_t ws_size,
                              hipStream_t stream) {
    const float* x  = (const float*)d_in[0];
    const float* W1 = (const float*)d_in[1];
    const float* b1 = (const float*)d_in[2];
    const float* W2 = (const float*)d_in[3];
    const float* b2 = (const float*)d_in[4];
    const float* a  = (const float*)d_in[5];
    float* A = (float*)d_out;

    float* L = (float*)d_ws;                 // 1 MB
    float* R = L + NN * TT * DD;             // 1 MB

    k1_proj<<<512, 256, 0, stream>>>(x, W1, b1, L, R);

    size_t ldsBytes = (32768 + 64) * sizeof(float);   // ~128.3 KB
    k2_main<<<dim3(16, 16), 512, ldsBytes, stream>>>(L, R, W2, b2, a, A);
}